// Round 5
// baseline (84.746 us; speedup 1.0000x reference)
//
#include <hip/hip_runtime.h>
#include <math.h>

// Luong attention, fused single pass over enc (read exactly once).
// R5: (a) block's 4 waves walk ONE contiguous region in lockstep
//     (16 KiB/iteration-step) -> 2048 streams instead of 8192;
//     (b) 16-lane-group layout: each group owns one row/iteration,
//     score reduce = 4 shuffles per 4 rows (was 6 per row);
//     (c) per-wave partials, no intra-block combine/sync in k1.

#define BLOCK 256
#define D 256
#define WPB 4             // waves per block
#define ROWS_PER_ITER 16  // rows consumed per block per iteration (4 waves x 4 groups)

// Kernel 1: per-wave partial with online softmax.
// ws layout: pacc[nw_total][D] floats, then ml[nw_total][2].
__global__ __launch_bounds__(BLOCK, 8) void attn_partial(
    const float* __restrict__ enc,   // [B,T,D]
    const float* __restrict__ dec,   // [B,D]
    float* __restrict__ ws,
    int T, int P, int nw_total)
{
    const int blk   = blockIdx.x;
    const int b     = blk / P;
    const int chunk = blk % P;
    const int tid   = threadIdx.x;
    const int wave  = tid >> 6;
    const int lane  = tid & 63;
    const int g     = lane >> 4;   // 16-lane group: owns one row per iteration
    const int k     = lane & 15;   // lane-in-group: owns cols {j*64 + k*4 .. +3}

    const int rows_per_block = T / P;
    const int iters = rows_per_block / ROWS_PER_ITER;
    // iteration i: group (wave,g) handles row base + i*16
    const int base = chunk * rows_per_block + wave * 4 + g;

    const float* __restrict__ encb = enc + (size_t)b * T * D;
    const float* __restrict__ decb = dec + (size_t)b * D;

    // dec fragments for this lane's 16 columns
    const float4 dq0 = *reinterpret_cast<const float4*>(decb + 0 * 64 + k * 4);
    const float4 dq1 = *reinterpret_cast<const float4*>(decb + 1 * 64 + k * 4);
    const float4 dq2 = *reinterpret_cast<const float4*>(decb + 2 * 64 + k * 4);
    const float4 dq3 = *reinterpret_cast<const float4*>(decb + 3 * 64 + k * 4);

    float  m = -INFINITY;
    float  l = 0.0f;
    float4 a0 = {0,0,0,0}, a1 = {0,0,0,0}, a2 = {0,0,0,0}, a3 = {0,0,0,0};

    const float* rowp = encb + (size_t)base * D + k * 4;

    for (int i = 0; i < iters; ++i) {
        const float* rp = rowp + (size_t)i * ROWS_PER_ITER * D;
        const float4 x0 = *reinterpret_cast<const float4*>(rp + 0 * 64);
        const float4 x1 = *reinterpret_cast<const float4*>(rp + 1 * 64);
        const float4 x2 = *reinterpret_cast<const float4*>(rp + 2 * 64);
        const float4 x3 = *reinterpret_cast<const float4*>(rp + 3 * 64);

        float p = x0.x*dq0.x + x0.y*dq0.y + x0.z*dq0.z + x0.w*dq0.w;
        p = fmaf(x1.x, dq1.x, fmaf(x1.y, dq1.y, fmaf(x1.z, dq1.z, fmaf(x1.w, dq1.w, p))));
        p = fmaf(x2.x, dq2.x, fmaf(x2.y, dq2.y, fmaf(x2.z, dq2.z, fmaf(x2.w, dq2.w, p))));
        p = fmaf(x3.x, dq3.x, fmaf(x3.y, dq3.y, fmaf(x3.z, dq3.z, fmaf(x3.w, dq3.w, p))));

        // reduce within the 16-lane group (all 4 groups at once)
        p += __shfl_xor(p, 1, 64);
        p += __shfl_xor(p, 2, 64);
        p += __shfl_xor(p, 4, 64);
        p += __shfl_xor(p, 8, 64);

        // online softmax update (one new score per group)
        const float mn    = fmaxf(m, p);
        const float scale = __expf(m - mn);   // 0 when m == -inf
        const float w     = __expf(p - mn);

        a0.x = fmaf(w, x0.x, a0.x * scale); a0.y = fmaf(w, x0.y, a0.y * scale);
        a0.z = fmaf(w, x0.z, a0.z * scale); a0.w = fmaf(w, x0.w, a0.w * scale);
        a1.x = fmaf(w, x1.x, a1.x * scale); a1.y = fmaf(w, x1.y, a1.y * scale);
        a1.z = fmaf(w, x1.z, a1.z * scale); a1.w = fmaf(w, x1.w, a1.w * scale);
        a2.x = fmaf(w, x2.x, a2.x * scale); a2.y = fmaf(w, x2.y, a2.y * scale);
        a2.z = fmaf(w, x2.z, a2.z * scale); a2.w = fmaf(w, x2.w, a2.w * scale);
        a3.x = fmaf(w, x3.x, a3.x * scale); a3.y = fmaf(w, x3.y, a3.y * scale);
        a3.z = fmaf(w, x3.z, a3.z * scale); a3.w = fmaf(w, x3.w, a3.w * scale);
        l = fmaf(l, scale, w);
        m = mn;
    }

    // ---- combine the 4 groups within the wave (register shuffles only) ----
    float M = fmaxf(m, __shfl_xor(m, 16, 64));
    M = fmaxf(M, __shfl_xor(M, 32, 64));
    const float e = __expf(m - M);
    l *= e;
    a0.x *= e; a0.y *= e; a0.z *= e; a0.w *= e;
    a1.x *= e; a1.y *= e; a1.z *= e; a1.w *= e;
    a2.x *= e; a2.y *= e; a2.z *= e; a2.w *= e;
    a3.x *= e; a3.y *= e; a3.z *= e; a3.w *= e;

    l += __shfl_xor(l, 16, 64); l += __shfl_xor(l, 32, 64);
#define RED2(c) c += __shfl_xor(c, 16, 64); c += __shfl_xor(c, 32, 64)
    RED2(a0.x); RED2(a0.y); RED2(a0.z); RED2(a0.w);
    RED2(a1.x); RED2(a1.y); RED2(a1.z); RED2(a1.w);
    RED2(a2.x); RED2(a2.y); RED2(a2.z); RED2(a2.w);
    RED2(a3.x); RED2(a3.y); RED2(a3.z); RED2(a3.w);
#undef RED2

    // lane writes cols g*64 + k*4 (== lane*4): pick acc_g without runtime index
    const float4 lo = (g & 1) ? a1 : a0;
    const float4 hi = (g & 1) ? a3 : a2;
    const float4 v  = (g & 2) ? hi : lo;

    const int wid = blk * WPB + wave;
    *reinterpret_cast<float4*>(ws + (size_t)wid * D + lane * 4) = v;
    if (lane == 0) {
        float* ml = ws + (size_t)nw_total * D;
        ml[wid * 2 + 0] = M;
        ml[wid * 2 + 1] = l;   // wave-total L (post-reduce, wave-uniform)
    }
}

// Kernel 2: combine nw per-wave partials per batch, normalize, write out.
// grid = B*4 blocks; block handles one 64-column quarter.
__global__ __launch_bounds__(BLOCK) void attn_combine(
    const float* __restrict__ ws,
    float* __restrict__ out,
    int nw, int nw_total)
{
    const int b     = blockIdx.x >> 2;
    const int cq    = blockIdx.x & 3;
    const int tid   = threadIdx.x;
    const int lane  = tid & 63;
    const int slice = tid >> 6;
    const int col   = cq * 64 + lane;
    const int i0    = b * nw;

    const float* __restrict__ ml = ws + (size_t)nw_total * D;

    __shared__ float sM[4];
    __shared__ float sL[4];
    __shared__ float sA[4][64];

    float Mw = -INFINITY;
    for (int i = slice; i < nw; i += 4)
        Mw = fmaxf(Mw, ml[(i0 + i) * 2 + 0]);
    if (lane == 0) sM[slice] = Mw;
    __syncthreads();
    const float M = fmaxf(fmaxf(sM[0], sM[1]), fmaxf(sM[2], sM[3]));

    float a = 0.0f, L = 0.0f;
    for (int i = slice; i < nw; i += 4) {
        const int pid = i0 + i;
        const float e = __expf(ml[pid * 2 + 0] - M);
        a = fmaf(e, ws[(size_t)pid * D + col], a);
        L = fmaf(e, ml[pid * 2 + 1], L);
    }
    sA[slice][lane] = a;
    if (lane == 0) sL[slice] = L;
    __syncthreads();

    if (slice == 0) {
        const float at = sA[0][lane] + sA[1][lane] + sA[2][lane] + sA[3][lane];
        const float Lt = sL[0] + sL[1] + sL[2] + sL[3];
        out[b * D + col] = at / Lt;
    }
}

extern "C" void kernel_launch(void* const* d_in, const int* in_sizes, int n_in,
                              void* d_out, int out_size, void* d_ws, size_t ws_size,
                              hipStream_t stream) {
    const float* enc = (const float*)d_in[0];
    const float* dec = (const float*)d_in[1];
    float* out = (float*)d_out;
    float* ws  = (float*)d_ws;

    const int B = in_sizes[1] / D;              // dec is [B, D]
    const int T = in_sizes[0] / in_sizes[1];    // enc is [B, T, D]

    // P chunks per batch; shrink if workspace too small or shape not divisible.
    int P = 64;
    while (P > 1 && ((size_t)B * P * WPB * (D + 2) * sizeof(float)) > ws_size) P >>= 1;
    while (P > 1 && (T % (P * ROWS_PER_ITER) != 0)) P >>= 1;

    const int nblk     = B * P;
    const int nw_total = nblk * WPB;
    attn_partial<<<nblk, BLOCK, 0, stream>>>(enc, dec, ws, T, P, nw_total);
    attn_combine<<<B * 4, BLOCK, 0, stream>>>(ws, out, P * WPB, nw_total);
}

// Round 6
// 84.698 us; speedup vs baseline: 1.0006x; 1.0006x over previous
//
#include <hip/hip_runtime.h>
#include <math.h>

// Luong attention, fused single pass over enc (read exactly once).
// R6 = R5 with the spill bug fixed: R5's __launch_bounds__(256,8) forced a
// 64-VGPR cap onto a ~80-VGPR loop -> scratch spills -> 85us. No min-waves
// clause now; compiler allocates freely (memory-bound, 5-6 waves/SIMD is
// ample). Layout (per-16-lane-group row ownership): exp instr/row 1.25->0.5,
// shuffle instr/row 6->1 vs R4.

#define BLOCK 256
#define D 256
#define WPB 4             // waves per block
#define ROWS_PER_ITER 16  // rows consumed per block per iteration (4 waves x 4 groups)

// Kernel 1: per-wave partial with online softmax.
// ws layout: pacc[nw_total][D] floats, then ml[nw_total][2].
__global__ __launch_bounds__(BLOCK) void attn_partial(
    const float* __restrict__ enc,   // [B,T,D]
    const float* __restrict__ dec,   // [B,D]
    float* __restrict__ ws,
    int T, int P, int nw_total)
{
    const int blk   = blockIdx.x;
    const int b     = blk / P;
    const int chunk = blk % P;
    const int tid   = threadIdx.x;
    const int wave  = tid >> 6;
    const int lane  = tid & 63;
    const int g     = lane >> 4;   // 16-lane group: owns one row per iteration
    const int k     = lane & 15;   // lane-in-group: owns cols {j*64 + k*4 .. +3}

    const int rows_per_block = T / P;
    const int iters = rows_per_block / ROWS_PER_ITER;
    // iteration i: group (wave,g) handles row base + i*16
    const int base = chunk * rows_per_block + wave * 4 + g;

    const float* __restrict__ encb = enc + (size_t)b * T * D;
    const float* __restrict__ decb = dec + (size_t)b * D;

    // dec fragments for this lane's 16 columns
    const float4 dq0 = *reinterpret_cast<const float4*>(decb + 0 * 64 + k * 4);
    const float4 dq1 = *reinterpret_cast<const float4*>(decb + 1 * 64 + k * 4);
    const float4 dq2 = *reinterpret_cast<const float4*>(decb + 2 * 64 + k * 4);
    const float4 dq3 = *reinterpret_cast<const float4*>(decb + 3 * 64 + k * 4);

    float  m = -INFINITY;
    float  l = 0.0f;
    float4 a0 = {0,0,0,0}, a1 = {0,0,0,0}, a2 = {0,0,0,0}, a3 = {0,0,0,0};

    const float* rowp = encb + (size_t)base * D + k * 4;

    #pragma unroll 2
    for (int i = 0; i < iters; ++i) {
        const float* rp = rowp + (size_t)i * ROWS_PER_ITER * D;
        const float4 x0 = *reinterpret_cast<const float4*>(rp + 0 * 64);
        const float4 x1 = *reinterpret_cast<const float4*>(rp + 1 * 64);
        const float4 x2 = *reinterpret_cast<const float4*>(rp + 2 * 64);
        const float4 x3 = *reinterpret_cast<const float4*>(rp + 3 * 64);

        float p = x0.x*dq0.x + x0.y*dq0.y + x0.z*dq0.z + x0.w*dq0.w;
        p = fmaf(x1.x, dq1.x, fmaf(x1.y, dq1.y, fmaf(x1.z, dq1.z, fmaf(x1.w, dq1.w, p))));
        p = fmaf(x2.x, dq2.x, fmaf(x2.y, dq2.y, fmaf(x2.z, dq2.z, fmaf(x2.w, dq2.w, p))));
        p = fmaf(x3.x, dq3.x, fmaf(x3.y, dq3.y, fmaf(x3.z, dq3.z, fmaf(x3.w, dq3.w, p))));

        // reduce within the 16-lane group (all 4 groups at once)
        p += __shfl_xor(p, 1, 64);
        p += __shfl_xor(p, 2, 64);
        p += __shfl_xor(p, 4, 64);
        p += __shfl_xor(p, 8, 64);

        // online softmax update (one new score per group)
        const float mn    = fmaxf(m, p);
        const float scale = __expf(m - mn);   // 0 when m == -inf
        const float w     = __expf(p - mn);

        a0.x = fmaf(w, x0.x, a0.x * scale); a0.y = fmaf(w, x0.y, a0.y * scale);
        a0.z = fmaf(w, x0.z, a0.z * scale); a0.w = fmaf(w, x0.w, a0.w * scale);
        a1.x = fmaf(w, x1.x, a1.x * scale); a1.y = fmaf(w, x1.y, a1.y * scale);
        a1.z = fmaf(w, x1.z, a1.z * scale); a1.w = fmaf(w, x1.w, a1.w * scale);
        a2.x = fmaf(w, x2.x, a2.x * scale); a2.y = fmaf(w, x2.y, a2.y * scale);
        a2.z = fmaf(w, x2.z, a2.z * scale); a2.w = fmaf(w, x2.w, a2.w * scale);
        a3.x = fmaf(w, x3.x, a3.x * scale); a3.y = fmaf(w, x3.y, a3.y * scale);
        a3.z = fmaf(w, x3.z, a3.z * scale); a3.w = fmaf(w, x3.w, a3.w * scale);
        l = fmaf(l, scale, w);
        m = mn;
    }

    // ---- combine the 4 groups within the wave (register shuffles only) ----
    float M = fmaxf(m, __shfl_xor(m, 16, 64));
    M = fmaxf(M, __shfl_xor(M, 32, 64));
    const float e = __expf(m - M);
    l *= e;
    a0.x *= e; a0.y *= e; a0.z *= e; a0.w *= e;
    a1.x *= e; a1.y *= e; a1.z *= e; a1.w *= e;
    a2.x *= e; a2.y *= e; a2.z *= e; a2.w *= e;
    a3.x *= e; a3.y *= e; a3.z *= e; a3.w *= e;

    l += __shfl_xor(l, 16, 64); l += __shfl_xor(l, 32, 64);
#define RED2(c) c += __shfl_xor(c, 16, 64); c += __shfl_xor(c, 32, 64)
    RED2(a0.x); RED2(a0.y); RED2(a0.z); RED2(a0.w);
    RED2(a1.x); RED2(a1.y); RED2(a1.z); RED2(a1.w);
    RED2(a2.x); RED2(a2.y); RED2(a2.z); RED2(a2.w);
    RED2(a3.x); RED2(a3.y); RED2(a3.z); RED2(a3.w);
#undef RED2

    // lane writes cols g*64 + k*4 (== lane*4): pick acc_g without runtime index
    const float4 lo = (g & 1) ? a1 : a0;
    const float4 hi = (g & 1) ? a3 : a2;
    const float4 v  = (g & 2) ? hi : lo;

    const int wid = blk * WPB + wave;
    *reinterpret_cast<float4*>(ws + (size_t)wid * D + lane * 4) = v;
    if (lane == 0) {
        float* ml = ws + (size_t)nw_total * D;
        ml[wid * 2 + 0] = M;
        ml[wid * 2 + 1] = l;   // wave-total L (post-reduce, wave-uniform)
    }
}

// Kernel 2: combine nw per-wave partials per batch, normalize, write out.
// grid = B*4 blocks; block handles one 64-column quarter.
__global__ __launch_bounds__(BLOCK) void attn_combine(
    const float* __restrict__ ws,
    float* __restrict__ out,
    int nw, int nw_total)
{
    const int b     = blockIdx.x >> 2;
    const int cq    = blockIdx.x & 3;
    const int tid   = threadIdx.x;
    const int lane  = tid & 63;
    const int slice = tid >> 6;
    const int col   = cq * 64 + lane;
    const int i0    = b * nw;

    const float* __restrict__ ml = ws + (size_t)nw_total * D;

    __shared__ float sM[4];
    __shared__ float sL[4];
    __shared__ float sA[4][64];

    float Mw = -INFINITY;
    for (int i = slice; i < nw; i += 4)
        Mw = fmaxf(Mw, ml[(i0 + i) * 2 + 0]);
    if (lane == 0) sM[slice] = Mw;
    __syncthreads();
    const float M = fmaxf(fmaxf(sM[0], sM[1]), fmaxf(sM[2], sM[3]));

    float a = 0.0f, L = 0.0f;
    for (int i = slice; i < nw; i += 4) {
        const int pid = i0 + i;
        const float e = __expf(ml[pid * 2 + 0] - M);
        a = fmaf(e, ws[(size_t)pid * D + col], a);
        L = fmaf(e, ml[pid * 2 + 1], L);
    }
    sA[slice][lane] = a;
    if (lane == 0) sL[slice] = L;
    __syncthreads();

    if (slice == 0) {
        const float at = sA[0][lane] + sA[1][lane] + sA[2][lane] + sA[3][lane];
        const float Lt = sL[0] + sL[1] + sL[2] + sL[3];
        out[b * D + col] = at / Lt;
    }
}

extern "C" void kernel_launch(void* const* d_in, const int* in_sizes, int n_in,
                              void* d_out, int out_size, void* d_ws, size_t ws_size,
                              hipStream_t stream) {
    const float* enc = (const float*)d_in[0];
    const float* dec = (const float*)d_in[1];
    float* out = (float*)d_out;
    float* ws  = (float*)d_ws;

    const int B = in_sizes[1] / D;              // dec is [B, D]
    const int T = in_sizes[0] / in_sizes[1];    // enc is [B, T, D]

    // P chunks per batch; shrink if workspace too small or shape not divisible.
    int P = 64;
    while (P > 1 && ((size_t)B * P * WPB * (D + 2) * sizeof(float)) > ws_size) P >>= 1;
    while (P > 1 && (T % (P * ROWS_PER_ITER) != 0)) P >>= 1;

    const int nblk     = B * P;
    const int nw_total = nblk * WPB;
    attn_partial<<<nblk, BLOCK, 0, stream>>>(enc, dec, ws, T, P, nw_total);
    attn_combine<<<B * 4, BLOCK, 0, stream>>>(ws, out, P * WPB, nw_total);
}

// Round 7
// 58.419 us; speedup vs baseline: 1.4507x; 1.4498x over previous
//
#include <hip/hip_runtime.h>
#include <math.h>

// Luong attention, fused single pass over enc (read exactly once).
// R7 = R4 structure (28 VGPR, 8 blocks/CU) with ONE change: the 4 waves of a
// block interleave in 16-row stripes, so each block walks a single contiguous
// 128 KB stream (2048 streams total) instead of 4 separate 32 KB streams
// (8192 streams). Isolates DRAM-stream fragmentation at constant occupancy.
// (R5/R6's 16-lane-group layout regressed 60->85us: 4x register pressure ->
// occupancy drop, NOT spills -- identical time with/without launch_bounds.)

#define WAVES_PER_BLOCK 4
#define BLOCK 256
#define D 256
#define RBATCH 4

// Kernel 1: per-(batch,chunk) partial with online softmax.
// ws layout: acc[B*P][256] floats, then interleaved (m,l)[B*P][2].
__global__ __launch_bounds__(BLOCK) void attn_partial(
    const float* __restrict__ enc,   // [B,T,D]
    const float* __restrict__ dec,   // [B,D]
    float* __restrict__ ws,
    int T, int P, int nblk_total)
{
    const int blk   = blockIdx.x;
    const int b     = blk / P;
    const int chunk = blk % P;
    const int tid   = threadIdx.x;
    const int wave  = tid >> 6;
    const int lane  = tid & 63;

    const int rows_per_block = T / P;
    const int steps = rows_per_block / (WAVES_PER_BLOCK * RBATCH);

    const float* __restrict__ encb = enc + (size_t)b * T * D;
    const float4 dq = *reinterpret_cast<const float4*>(dec + b * D + lane * 4);

    float  m = -INFINITY;
    float  l = 0.0f;
    float4 acc = {0.0f, 0.0f, 0.0f, 0.0f};

    // step s: wave handles rows chunk*rpb + s*16 + wave*4 .. +3
    const float* wbase = encb
        + (size_t)(chunk * rows_per_block + wave * RBATCH) * D + lane * 4;

    #pragma unroll 2
    for (int s = 0; s < steps; ++s) {
        const float* base = wbase + (size_t)s * (WAVES_PER_BLOCK * RBATCH) * D;
        const float4 x0 = *reinterpret_cast<const float4*>(base);
        const float4 x1 = *reinterpret_cast<const float4*>(base + D);
        const float4 x2 = *reinterpret_cast<const float4*>(base + 2 * D);
        const float4 x3 = *reinterpret_cast<const float4*>(base + 3 * D);

        float p0 = dq.x * x0.x + dq.y * x0.y + dq.z * x0.z + dq.w * x0.w;
        float p1 = dq.x * x1.x + dq.y * x1.y + dq.z * x1.z + dq.w * x1.w;
        float p2 = dq.x * x2.x + dq.y * x2.y + dq.z * x2.z + dq.w * x2.w;
        float p3 = dq.x * x3.x + dq.y * x3.y + dq.z * x3.z + dq.w * x3.w;

        #pragma unroll
        for (int off = 32; off >= 1; off >>= 1) {
            p0 += __shfl_xor(p0, off, 64);
            p1 += __shfl_xor(p1, off, 64);
            p2 += __shfl_xor(p2, off, 64);
            p3 += __shfl_xor(p3, off, 64);
        }

        const float mn    = fmaxf(fmaxf(fmaxf(p0, p1), fmaxf(p2, p3)), m);
        const float scale = __expf(m - mn);   // 0 when m == -inf
        const float w0 = __expf(p0 - mn);
        const float w1 = __expf(p1 - mn);
        const float w2 = __expf(p2 - mn);
        const float w3 = __expf(p3 - mn);

        acc.x = fmaf(w3, x3.x, fmaf(w2, x2.x, fmaf(w1, x1.x, fmaf(w0, x0.x, acc.x * scale))));
        acc.y = fmaf(w3, x3.y, fmaf(w2, x2.y, fmaf(w1, x1.y, fmaf(w0, x0.y, acc.y * scale))));
        acc.z = fmaf(w3, x3.z, fmaf(w2, x2.z, fmaf(w1, x1.z, fmaf(w0, x0.z, acc.z * scale))));
        acc.w = fmaf(w3, x3.w, fmaf(w2, x2.w, fmaf(w1, x1.w, fmaf(w0, x0.w, acc.w * scale))));
        l = fmaf(l, scale, w0 + w1 + w2 + w3);
        m = mn;
    }

    // combine the 4 waves' partials in LDS -> one partial per block
    __shared__ float s_acc[WAVES_PER_BLOCK][D];
    __shared__ float s_m[WAVES_PER_BLOCK];
    __shared__ float s_l[WAVES_PER_BLOCK];

    *reinterpret_cast<float4*>(&s_acc[wave][lane * 4]) = acc;
    if (lane == 0) { s_m[wave] = m; s_l[wave] = l; }
    __syncthreads();

    if (wave == 0) {
        const float M = fmaxf(fmaxf(s_m[0], s_m[1]), fmaxf(s_m[2], s_m[3]));
        float4 a = {0.0f, 0.0f, 0.0f, 0.0f};
        float  L = 0.0f;
        #pragma unroll
        for (int wv = 0; wv < WAVES_PER_BLOCK; ++wv) {
            const float e = __expf(s_m[wv] - M);
            const float4 aw = *reinterpret_cast<const float4*>(&s_acc[wv][lane * 4]);
            a.x += e * aw.x; a.y += e * aw.y; a.z += e * aw.z; a.w += e * aw.w;
            L += e * s_l[wv];
        }
        *reinterpret_cast<float4*>(ws + (size_t)blk * D + lane * 4) = a;
        if (lane == 0) {
            float* ml = ws + (size_t)nblk_total * D;
            ml[blk * 2 + 0] = M;
            ml[blk * 2 + 1] = L;
        }
    }
}

// Kernel 2: combine P partials per batch, normalize, write out.
// grid = B*4 blocks; block handles one 64-column quarter;
// 4 wave-slices stride the P loop, LDS reduce.
__global__ __launch_bounds__(BLOCK) void attn_combine(
    const float* __restrict__ ws,
    float* __restrict__ out,
    int P, int nblk_total)
{
    const int b     = blockIdx.x >> 2;
    const int cq    = blockIdx.x & 3;
    const int tid   = threadIdx.x;
    const int lane  = tid & 63;
    const int slice = tid >> 6;
    const int col   = cq * 64 + lane;

    const float* __restrict__ ml = ws + (size_t)nblk_total * D;

    float M = -INFINITY;
    for (int i = 0; i < P; ++i)
        M = fmaxf(M, ml[(b * P + i) * 2 + 0]);

    float a = 0.0f, L = 0.0f;
    for (int i = slice; i < P; i += 4) {
        const int pblk = b * P + i;
        const float e  = __expf(ml[pblk * 2 + 0] - M);
        a = fmaf(e, ws[(size_t)pblk * D + col], a);
        L = fmaf(e, ml[pblk * 2 + 1], L);
    }

    __shared__ float s_a[4][64];
    __shared__ float s_L[4];
    s_a[slice][lane] = a;
    if (lane == 0) s_L[slice] = L;
    __syncthreads();

    if (slice == 0) {
        const float at = s_a[0][lane] + s_a[1][lane] + s_a[2][lane] + s_a[3][lane];
        const float Lt = s_L[0] + s_L[1] + s_L[2] + s_L[3];
        out[b * D + col] = at / Lt;
    }
}

extern "C" void kernel_launch(void* const* d_in, const int* in_sizes, int n_in,
                              void* d_out, int out_size, void* d_ws, size_t ws_size,
                              hipStream_t stream) {
    const float* enc = (const float*)d_in[0];
    const float* dec = (const float*)d_in[1];
    float* out = (float*)d_out;
    float* ws  = (float*)d_ws;

    const int B = in_sizes[1] / D;              // dec is [B, D]
    const int T = in_sizes[0] / in_sizes[1];    // enc is [B, T, D]

    // P chunks per batch; shrink if workspace is small or shape not divisible.
    int P = 64;
    while (P > 1 && ((size_t)B * P * (D + 2) * sizeof(float)) > ws_size) P >>= 1;
    while (P > 1 && (T % (P * WAVES_PER_BLOCK * RBATCH) != 0)) P >>= 1;

    const int nblk = B * P;
    attn_partial<<<nblk, BLOCK, 0, stream>>>(enc, dec, ws, T, P, nblk);
    attn_combine<<<B * 4, BLOCK, 0, stream>>>(ws, out, P, nblk);
}